// Round 2
// baseline (24119.836 us; speedup 1.0000x reference)
//
#include <hip/hip_runtime.h>
#include <cstddef>
#include <math.h>

// Problem: B=64, S=1024, F=128, H=512, V=64, T=64. ALL floats are f32 (ref uses
// jnp.float32); target is int32; output f32 [B,T,V] log-softmax.
#define NWG 32
#define BB  64
#define HH  512
#define TT  64
#define VV  64
#define FF  128
#define SS  1024

typedef _Float16 f16;
typedef _Float16 f16x8 __attribute__((ext_vector_type(8)));
typedef float    f32x4 __attribute__((ext_vector_type(4)));

#define C1 4.8828125e-4f          // 2^-11
#define C2 2.384185791015625e-7f  // 2^-22

__device__ __forceinline__ void split8(const float* __restrict__ p, f16x8& hi, f16x8& lo) {
  f32x4 u = *(const f32x4*)p;
  f32x4 v = *(const f32x4*)(p + 4);
#pragma unroll
  for (int j = 0; j < 4; ++j) {
    f16 a = (f16)u[j]; hi[j]   = a; lo[j]   = (f16)((u[j] - (float)a) * 2048.0f);
    f16 b = (f16)v[j]; hi[4+j] = b; lo[4+j] = (f16)((v[j] - (float)b) * 2048.0f);
  }
}
__device__ __forceinline__ f16x8 ldh8(const f16* p) { return *(const f16x8*)p; }
__device__ __forceinline__ float sigmf_(float x) { return 1.0f / (1.0f + expf(-x)); }

// Grid barrier: 32 co-resident WGs, monotone counter, device(agent)-scope.
__device__ __forceinline__ void gsync(unsigned* cnt, unsigned target) {
  __threadfence();
  __syncthreads();
  if (threadIdx.x == 0) {
    __hip_atomic_fetch_add(cnt, 1u, __ATOMIC_ACQ_REL, __HIP_MEMORY_SCOPE_AGENT);
    while (__hip_atomic_load(cnt, __ATOMIC_ACQUIRE, __HIP_MEMORY_SCOPE_AGENT) < target)
      __builtin_amdgcn_s_sleep(1);
  }
  __syncthreads();
  __threadfence();
}

#define MFMA(d, a, b) d = __builtin_amdgcn_mfma_f32_16x16x32_f16(a, b, d, 0, 0, 0)

__global__ void __launch_bounds__(256, 1) lstm_seq2seq(
    const float* __restrict__ sig,   // [B,S,F]
    const int*   __restrict__ tgt,   // [B,T]
    const float* __restrict__ eWih,  // [2048,128]
    const float* __restrict__ eWhh,  // [2048,512]
    const float* __restrict__ eBih,  // [2048]
    const float* __restrict__ eBhh,  // [2048]
    const float* __restrict__ dWih,  // [2048,64]
    const float* __restrict__ dWhh,  // [2048,512]
    const float* __restrict__ dBih,  // [2048]
    const float* __restrict__ dBhh,  // [2048]
    const float* __restrict__ oW,    // [64,512]
    const float* __restrict__ oB,    // [64]
    float*       __restrict__ out,   // [B,T,V]
    unsigned char* __restrict__ ws)
{
  unsigned* cnt = (unsigned*)ws;
  int* idxbuf   = (int*)(ws + 256);
  f16* hhi[2] = { (f16*)(ws + 1024),   (f16*)(ws + 1024 + 65536) };
  f16* hlo[2] = { (f16*)(ws + 132096), (f16*)(ws + 132096 + 65536) };
  float* hf32[2] = { (float*)(ws + 263168), (float*)(ws + 263168 + 131072) };

  const int tid   = threadIdx.x;
  const int p     = blockIdx.x;     // WG owns h-dims [p*16, p*16+16) per gate
  const int w     = tid >> 6;
  const int lane  = tid & 63;
  const int q     = lane >> 4;      // MFMA quad: A/B k = q*8+j ; C/D row = q*4+r
  const int mn    = lane & 15;      // A row (m) / B col (n) / C col
  const int bhalf = w >> 1;         // batch rows [bhalf*32, +32)
  const int dhalf = w & 1;          // local gate-dims [dhalf*32, +32)

  __shared__ f16 xwh[64][136];      // eWih slice, hi split (row pad 8 -> no 2^k stride)
  __shared__ f16 xwl[64][136];      // eWih slice, lo split (x2048)
  __shared__ float gate_buf[4][64][17];
  __shared__ float bias_buf[4][16];

  // ---- encoder weights: W_hh hi/lo fragments in registers ----
  // B-frag (16x16x32): lane(q,n) holds W[dim(n)][s*32 + q*8 .. +7]
  f16x8 fhhh[2][16], fhhl[2][16];
#pragma unroll
  for (int nt = 0; nt < 2; ++nt) {
    int dl  = dhalf*32 + nt*16 + mn;             // local gate-dim 0..63
    int row = (dl >> 4)*HH + p*16 + (dl & 15);   // row of W [4H x K]
#pragma unroll
    for (int s = 0; s < 16; ++s)
      split8(eWhh + (size_t)row*HH + s*32 + q*8, fhhh[nt][s], fhhl[nt][s]);
  }
  // eWih slice -> LDS (hi/lo)
  for (int idx = tid; idx < 64*128; idx += 256) {
    int dl = idx >> 7, k = idx & 127;
    int row = (dl >> 4)*HH + p*16 + (dl & 15);
    float x = eWih[row*FF + k];
    f16 a = (f16)x;
    xwh[dl][k] = a;
    xwl[dl][k] = (f16)((x - (float)a) * 2048.0f);
  }
  if (tid < 64) {
    int g = tid >> 4, kl = tid & 15;
    int r = g*HH + p*16 + kl;
    bias_buf[g][kl] = eBih[r] + eBhh[r];
  }
  __syncthreads();

  float c_reg[4] = {0.f, 0.f, 0.f, 0.f};
  const int eb  = tid >> 2;          // cell batch
  const int ek0 = (tid & 3) * 4;     // cell k-local base

  unsigned sync_no = 0;
  int cur = 0;                       // h double buffer (zeroed by memset = h0)
  const f32x4 zero4 = {0.f, 0.f, 0.f, 0.f};

  // ================= encoder: 1024 steps =================
  for (int t = 0; t < SS; ++t) {
    f32x4 acc0[4] = {zero4, zero4, zero4, zero4};   // [rt*2+nt]
    f32x4 acc1[4] = {zero4, zero4, zero4, zero4};
    f32x4 acc2[4] = {zero4, zero4, zero4, zero4};

    // ---- x part (K=128): split signal on the fly, B from LDS ----
    const float* sb0 = sig + (size_t)(bhalf*32 + mn)*(SS*FF) + (size_t)t*FF;
    const float* sb1 = sb0 + (size_t)16*(SS*FF);
#pragma unroll
    for (int s = 0; s < 4; ++s) {
      f16x8 a0h, a0l, a1h, a1l;
      split8(sb0 + s*32 + q*8, a0h, a0l);
      split8(sb1 + s*32 + q*8, a1h, a1l);
#pragma unroll
      for (int nt = 0; nt < 2; ++nt) {
        int dl = dhalf*32 + nt*16 + mn;
        f16x8 bh = ldh8(&xwh[dl][s*32 + q*8]);
        f16x8 bl = ldh8(&xwl[dl][s*32 + q*8]);
        MFMA(acc0[0+nt], a0h, bh);  MFMA(acc0[2+nt], a1h, bh);
        MFMA(acc1[0+nt], a0l, bh);  MFMA(acc1[2+nt], a1l, bh);
        MFMA(acc1[0+nt], a0h, bl);  MFMA(acc1[2+nt], a1h, bl);
        MFMA(acc2[0+nt], a0l, bl);  MFMA(acc2[2+nt], a1l, bl);
      }
    }
    // ---- h part (K=512): A from f16 hi/lo buffers, B in registers ----
    {
      const f16* h0h = hhi[cur] + (bhalf*32 + mn)*HH;
      const f16* h0l = hlo[cur] + (bhalf*32 + mn)*HH;
#pragma unroll
      for (int s = 0; s < 16; ++s) {
        f16x8 a0h = ldh8(h0h + s*32 + q*8);
        f16x8 a0l = ldh8(h0l + s*32 + q*8);
        f16x8 a1h = ldh8(h0h + 16*HH + s*32 + q*8);
        f16x8 a1l = ldh8(h0l + 16*HH + s*32 + q*8);
#pragma unroll
        for (int nt = 0; nt < 2; ++nt) {
          MFMA(acc0[0+nt], a0h, fhhh[nt][s]);  MFMA(acc0[2+nt], a1h, fhhh[nt][s]);
          MFMA(acc1[0+nt], a0l, fhhh[nt][s]);  MFMA(acc1[2+nt], a1l, fhhh[nt][s]);
          MFMA(acc1[0+nt], a0h, fhhl[nt][s]);  MFMA(acc1[2+nt], a1h, fhhl[nt][s]);
          MFMA(acc2[0+nt], a0l, fhhl[nt][s]);  MFMA(acc2[2+nt], a1l, fhhl[nt][s]);
        }
      }
    }
    // combine splits -> f32 gates, exchange via LDS (C/D: col=mn, row=q*4+r)
#pragma unroll
    for (int rt = 0; rt < 2; ++rt)
#pragma unroll
      for (int nt = 0; nt < 2; ++nt) {
        int i = rt*2 + nt;
#pragma unroll
        for (int r = 0; r < 4; ++r) {
          float g = acc0[i][r] + C1*acc1[i][r] + C2*acc2[i][r];
          gate_buf[dhalf*2 + nt][bhalf*32 + rt*16 + q*4 + r][mn] = g;
        }
      }
    __syncthreads();
    // LSTM cell on owned cells (f32, precise libm)
#pragma unroll
    for (int j = 0; j < 4; ++j) {
      int kl = ek0 + j;
      float gi = gate_buf[0][eb][kl] + bias_buf[0][kl];
      float gf = gate_buf[1][eb][kl] + bias_buf[1][kl];
      float gg = gate_buf[2][eb][kl] + bias_buf[2][kl];
      float go = gate_buf[3][eb][kl] + bias_buf[3][kl];
      float c  = sigmf_(gf)*c_reg[j] + sigmf_(gi)*tanhf(gg);
      float h  = sigmf_(go)*tanhf(c);
      c_reg[j] = c;
      int off = eb*HH + p*16 + kl;
      f16 hh = (f16)h;
      hhi[cur^1][off] = hh;
      hlo[cur^1][off] = (f16)((h - (float)hh) * 2048.0f);
    }
    sync_no += NWG;
    gsync(cnt, sync_no);
    cur ^= 1;
  }

  // ================= decoder setup =================
#pragma unroll
  for (int nt = 0; nt < 2; ++nt) {
    int dl  = dhalf*32 + nt*16 + mn;
    int row = (dl >> 4)*HH + p*16 + (dl & 15);
#pragma unroll
    for (int s = 0; s < 16; ++s)
      split8(dWhh + (size_t)row*HH + s*32 + q*8, fhhh[nt][s], fhhl[nt][s]);
  }
  if (tid < 64) {
    int g = tid >> 4, kl = tid & 15;
    int r = g*HH + p*16 + kl;
    bias_buf[g][kl] = dBih[r] + dBhh[r];
  }
  if (p == 0 && tid < 64) idxbuf[tid] = tgt[tid * TT];   // target[:,0]
  sync_no += NWG;
  gsync(cnt, sync_no);

  // ================= decoder: 64 steps =================
  for (int t = 0; t < TT; ++t) {
    // ---- phase A: cell. x = relu(one_hot(idx)) = one_hot -> column gather ----
    f32x4 acc0[4] = {zero4, zero4, zero4, zero4};
    f32x4 acc1[4] = {zero4, zero4, zero4, zero4};
    f32x4 acc2[4] = {zero4, zero4, zero4, zero4};
    {
      const f16* h0h = hhi[cur] + (bhalf*32 + mn)*HH;
      const f16* h0l = hlo[cur] + (bhalf*32 + mn)*HH;
#pragma unroll
      for (int s = 0; s < 16; ++s) {
        f16x8 a0h = ldh8(h0h + s*32 + q*8);
        f16x8 a0l = ldh8(h0l + s*32 + q*8);
        f16x8 a1h = ldh8(h0h + 16*HH + s*32 + q*8);
        f16x8 a1l = ldh8(h0l + 16*HH + s*32 + q*8);
#pragma unroll
        for (int nt = 0; nt < 2; ++nt) {
          MFMA(acc0[0+nt], a0h, fhhh[nt][s]);  MFMA(acc0[2+nt], a1h, fhhh[nt][s]);
          MFMA(acc1[0+nt], a0l, fhhh[nt][s]);  MFMA(acc1[2+nt], a1l, fhhh[nt][s]);
          MFMA(acc1[0+nt], a0h, fhhl[nt][s]);  MFMA(acc1[2+nt], a1h, fhhl[nt][s]);
          MFMA(acc2[0+nt], a0l, fhhl[nt][s]);  MFMA(acc2[2+nt], a1l, fhhl[nt][s]);
        }
      }
    }
#pragma unroll
    for (int rt = 0; rt < 2; ++rt)
#pragma unroll
      for (int nt = 0; nt < 2; ++nt) {
        int i = rt*2 + nt;
#pragma unroll
        for (int r = 0; r < 4; ++r) {
          float g = acc0[i][r] + C1*acc1[i][r] + C2*acc2[i][r];
          gate_buf[dhalf*2 + nt][bhalf*32 + rt*16 + q*4 + r][mn] = g;
        }
      }
    __syncthreads();
    {
      int ib = idxbuf[eb];
#pragma unroll
      for (int j = 0; j < 4; ++j) {
        int kl = ek0 + j;
        int rb = p*16 + kl;
        float gi = gate_buf[0][eb][kl] + bias_buf[0][kl] + dWih[(0*HH + rb)*VV + ib];
        float gf = gate_buf[1][eb][kl] + bias_buf[1][kl] + dWih[(1*HH + rb)*VV + ib];
        float gg = gate_buf[2][eb][kl] + bias_buf[2][kl] + dWih[(2*HH + rb)*VV + ib];
        float go = gate_buf[3][eb][kl] + bias_buf[3][kl] + dWih[(3*HH + rb)*VV + ib];
        float c  = sigmf_(gf)*c_reg[j] + sigmf_(gi)*tanhf(gg);
        float h  = sigmf_(go)*tanhf(c);
        c_reg[j] = c;
        int off = eb*HH + p*16 + kl;
        f16 hh = (f16)h;
        hhi[cur^1][off] = hh;
        hlo[cur^1][off] = (f16)((h - (float)hh) * 2048.0f);
        hf32[cur^1][off] = h;
      }
    }
    sync_no += NWG;
    gsync(cnt, sync_no);
    int nxt = cur ^ 1;

    // ---- phase B: f64 logits + argmax + log-softmax (waves 0,1; 1 row/wave) ----
    if (w < 2) {
      int b = p*2 + w;
      int v = lane;
      const float* hp = hf32[nxt] + b*HH;
      const float* wr = oW + v*HH;
      double acc = 0.0;
#pragma unroll 4
      for (int kc = 0; kc < 128; ++kc) {
        f32x4 hv = *(const f32x4*)(hp + kc*4);
        f32x4 wv = *(const f32x4*)(wr + kc*4);
        acc += (double)hv[0]*(double)wv[0] + (double)hv[1]*(double)wv[1]
             + (double)hv[2]*(double)wv[2] + (double)hv[3]*(double)wv[3];
      }
      double l = acc + (double)oB[v];
      double mx = l; int ai = v;
#pragma unroll
      for (int o = 32; o > 0; o >>= 1) {
        double om = __shfl_xor(mx, o, 64);
        int    oi = __shfl_xor(ai, o, 64);
        if (om > mx || (om == mx && oi < ai)) { mx = om; ai = oi; }
      }
      double se = exp(l - mx);
#pragma unroll
      for (int o = 32; o > 0; o >>= 1) se += __shfl_xor(se, o, 64);
      double lse = mx + log(se);
      out[((size_t)b*TT + t)*VV + v] = (float)(l - lse);
      if (lane == 0) idxbuf[b] = ai;
    }
    sync_no += NWG;
    gsync(cnt, sync_no);
    cur = nxt;
  }
}

extern "C" void kernel_launch(void* const* d_in, const int* in_sizes, int n_in,
                              void* d_out, int out_size, void* d_ws, size_t ws_size,
                              hipStream_t stream) {
  (void)in_sizes; (void)n_in; (void)out_size; (void)ws_size;
  // zero: counter + idxbuf + h16 hi/lo double-buffers + hf32 double-buffer
  // (ws is re-poisoned 0xAA before every launch -> must zero every call)
  size_t zbytes = 263168 + 262144;  // = 525312
  hipMemsetAsync(d_ws, 0, zbytes, stream);
  lstm_seq2seq<<<dim3(NWG), dim3(256), 0, stream>>>(
      (const float*)d_in[0],  (const int*)d_in[1],
      (const float*)d_in[2],  (const float*)d_in[3],
      (const float*)d_in[4],  (const float*)d_in[5],
      (const float*)d_in[6],  (const float*)d_in[7],
      (const float*)d_in[8],  (const float*)d_in[9],
      (const float*)d_in[10], (const float*)d_in[11],
      (float*)d_out, (unsigned char*)d_ws);
}

// Round 3
// 21417.039 us; speedup vs baseline: 1.1262x; 1.1262x over previous
//
#include <hip/hip_runtime.h>
#include <cstddef>
#include <math.h>

// Problem: B=64, S=1024, F=128, H=512, V=64, T=64. All floats f32; out f32.
// Design: 32 persistent WGs, W_hh hi/lo f16 Ootomo fragments register-resident,
// cross-WG h exchange via global ws + split-fence grid barrier.
// R3 change vs R2 (which passed, absmax 0.0, 24.8ms): the barrier. R2's
// __threadfence + ACQUIRE-poll issued buffer_wbl2+buffer_inv per wave per poll
// iteration -> 22.8us/step of L2-invalidate storms. Now: one RELEASE fence
// (tid0) before arrive, RELAXED poll (no cache ops), one ACQUIRE fence after
// exit; x-part MFMAs hoisted between arrive and wait.
#define NWG 32
#define BB  64
#define HH  512
#define TT  64
#define VV  64
#define FF  128
#define SS  1024

typedef _Float16 f16;
typedef _Float16 f16x8 __attribute__((ext_vector_type(8)));
typedef float    f32x4 __attribute__((ext_vector_type(4)));

#define C1 4.8828125e-4f          // 2^-11
#define C2 2.384185791015625e-7f  // 2^-22

__device__ __forceinline__ void split8(const float* __restrict__ p, f16x8& hi, f16x8& lo) {
  f32x4 u = *(const f32x4*)p;
  f32x4 v = *(const f32x4*)(p + 4);
#pragma unroll
  for (int j = 0; j < 4; ++j) {
    f16 a = (f16)u[j]; hi[j]   = a; lo[j]   = (f16)((u[j] - (float)a) * 2048.0f);
    f16 b = (f16)v[j]; hi[4+j] = b; lo[4+j] = (f16)((v[j] - (float)b) * 2048.0f);
  }
}
__device__ __forceinline__ f16x8 ldh8(const f16* p) { return *(const f16x8*)p; }
__device__ __forceinline__ float sigmf_(float x) { return 1.0f / (1.0f + expf(-x)); }

// ---- split grid barrier (32 co-resident WGs) ----
// arrive: drain own stores to L2, writeback L2 once (tid0), relaxed add.
// wait:   relaxed poll (NO cache maintenance in the loop), then one acquire
//         fence (buffer_inv) so subsequent normal loads see other XCDs' data.
__device__ __forceinline__ void g_arrive(unsigned* cnt) {
  asm volatile("s_waitcnt vmcnt(0)" ::: "memory");   // own stores at L2
  __syncthreads();                                   // whole WG's stores at L2
  if (threadIdx.x == 0) {
    __builtin_amdgcn_fence(__ATOMIC_RELEASE, "agent");  // wbl2 + completion wait
    __hip_atomic_fetch_add(cnt, 1u, __ATOMIC_RELAXED, __HIP_MEMORY_SCOPE_AGENT);
  }
}
__device__ __forceinline__ void g_wait(unsigned* cnt, unsigned target) {
  if (threadIdx.x == 0) {
    while (__hip_atomic_load(cnt, __ATOMIC_RELAXED, __HIP_MEMORY_SCOPE_AGENT) < target)
      __builtin_amdgcn_s_sleep(1);
  }
  __syncthreads();
  __builtin_amdgcn_fence(__ATOMIC_ACQUIRE, "agent");    // buffer_inv (L1+L2)
}

#define MFMA(d, a, b) d = __builtin_amdgcn_mfma_f32_16x16x32_f16(a, b, d, 0, 0, 0)

__global__ void __launch_bounds__(256, 1) lstm_seq2seq(
    const float* __restrict__ sig,   // [B,S,F]
    const int*   __restrict__ tgt,   // [B,T]
    const float* __restrict__ eWih,  // [2048,128]
    const float* __restrict__ eWhh,  // [2048,512]
    const float* __restrict__ eBih,  // [2048]
    const float* __restrict__ eBhh,  // [2048]
    const float* __restrict__ dWih,  // [2048,64]
    const float* __restrict__ dWhh,  // [2048,512]
    const float* __restrict__ dBih,  // [2048]
    const float* __restrict__ dBhh,  // [2048]
    const float* __restrict__ oW,    // [64,512]
    const float* __restrict__ oB,    // [64]
    float*       __restrict__ out,   // [B,T,V]
    unsigned char* __restrict__ ws)
{
  unsigned* cnt = (unsigned*)ws;
  int* idxbuf   = (int*)(ws + 256);
  f16* hhi[2] = { (f16*)(ws + 1024),   (f16*)(ws + 1024 + 65536) };
  f16* hlo[2] = { (f16*)(ws + 132096), (f16*)(ws + 132096 + 65536) };
  float* hf32[2] = { (float*)(ws + 263168), (float*)(ws + 263168 + 131072) };

  const int tid   = threadIdx.x;
  const int p     = blockIdx.x;     // WG owns h-dims [p*16, p*16+16) per gate
  const int w     = tid >> 6;
  const int lane  = tid & 63;
  const int q     = lane >> 4;      // MFMA quad: A/B k = q*8+j ; C/D row = q*4+r
  const int mn    = lane & 15;      // A row (m) / B col (n) / C col
  const int bhalf = w >> 1;         // batch rows [bhalf*32, +32)
  const int dhalf = w & 1;          // local gate-dims [dhalf*32, +32)

  __shared__ f16 xwh[64][136];      // eWih slice hi (pad 8: no 2^k stride)
  __shared__ f16 xwl[64][136];      // eWih slice lo (x2048)
  __shared__ float gate_buf[4][64][17];
  __shared__ float bias_buf[4][16];

  // ---- encoder weights: W_hh hi/lo fragments in registers ----
  f16x8 fhhh[2][16], fhhl[2][16];
#pragma unroll
  for (int nt = 0; nt < 2; ++nt) {
    int dl  = dhalf*32 + nt*16 + mn;             // local gate-dim 0..63
    int row = (dl >> 4)*HH + p*16 + (dl & 15);   // row of W [4H x K]
#pragma unroll
    for (int s = 0; s < 16; ++s)
      split8(eWhh + (size_t)row*HH + s*32 + q*8, fhhh[nt][s], fhhl[nt][s]);
  }
  for (int idx = tid; idx < 64*128; idx += 256) {
    int dl = idx >> 7, k = idx & 127;
    int row = (dl >> 4)*HH + p*16 + (dl & 15);
    float x = eWih[row*FF + k];
    f16 a = (f16)x;
    xwh[dl][k] = a;
    xwl[dl][k] = (f16)((x - (float)a) * 2048.0f);
  }
  if (tid < 64) {
    int g = tid >> 4, kl = tid & 15;
    int r = g*HH + p*16 + kl;
    bias_buf[g][kl] = eBih[r] + eBhh[r];
  }
  // idxbuf init moved up front (read-only source; flushed at first arrive)
  if (p == 0 && tid < 64) idxbuf[tid] = tgt[tid * TT];   // target[:,0]
  __syncthreads();

  float c_reg[4] = {0.f, 0.f, 0.f, 0.f};
  const int eb  = tid >> 2;          // cell batch
  const int ek0 = (tid & 3) * 4;     // cell k-local base

  int cur = 0;                       // h double buffer (zeroed by memset = h0)
  const f32x4 zero4 = {0.f, 0.f, 0.f, 0.f};

  // ================= encoder: 1024 steps =================
  for (int t = 0; t < SS; ++t) {
    f32x4 acc0[4] = {zero4, zero4, zero4, zero4};   // [rt*2+nt]
    f32x4 acc1[4] = {zero4, zero4, zero4, zero4};
    f32x4 acc2[4] = {zero4, zero4, zero4, zero4};

    // ---- x part (K=128): independent of h(t) -> overlaps barrier wait ----
    const float* sb0 = sig + (size_t)(bhalf*32 + mn)*(SS*FF) + (size_t)t*FF;
    const float* sb1 = sb0 + (size_t)16*(SS*FF);
#pragma unroll
    for (int s = 0; s < 4; ++s) {
      f16x8 a0h, a0l, a1h, a1l;
      split8(sb0 + s*32 + q*8, a0h, a0l);
      split8(sb1 + s*32 + q*8, a1h, a1l);
#pragma unroll
      for (int nt = 0; nt < 2; ++nt) {
        int dl = dhalf*32 + nt*16 + mn;
        f16x8 bh = ldh8(&xwh[dl][s*32 + q*8]);
        f16x8 bl = ldh8(&xwl[dl][s*32 + q*8]);
        MFMA(acc0[0+nt], a0h, bh);  MFMA(acc0[2+nt], a1h, bh);
        MFMA(acc1[0+nt], a0l, bh);  MFMA(acc1[2+nt], a1l, bh);
        MFMA(acc1[0+nt], a0h, bl);  MFMA(acc1[2+nt], a1h, bl);
        MFMA(acc2[0+nt], a0l, bl);  MFMA(acc2[2+nt], a1l, bl);
      }
    }
    // ---- h(t) now needed: wait for step-t availability ----
    g_wait(cnt, (unsigned)t * NWG);
    // ---- h part (K=512): A from f16 hi/lo buffers, B in registers ----
    {
      const f16* h0h = hhi[cur] + (bhalf*32 + mn)*HH;
      const f16* h0l = hlo[cur] + (bhalf*32 + mn)*HH;
#pragma unroll
      for (int s = 0; s < 16; ++s) {
        f16x8 a0h = ldh8(h0h + s*32 + q*8);
        f16x8 a0l = ldh8(h0l + s*32 + q*8);
        f16x8 a1h = ldh8(h0h + 16*HH + s*32 + q*8);
        f16x8 a1l = ldh8(h0l + 16*HH + s*32 + q*8);
#pragma unroll
        for (int nt = 0; nt < 2; ++nt) {
          MFMA(acc0[0+nt], a0h, fhhh[nt][s]);  MFMA(acc0[2+nt], a1h, fhhh[nt][s]);
          MFMA(acc1[0+nt], a0l, fhhh[nt][s]);  MFMA(acc1[2+nt], a1l, fhhh[nt][s]);
          MFMA(acc1[0+nt], a0h, fhhl[nt][s]);  MFMA(acc1[2+nt], a1h, fhhl[nt][s]);
          MFMA(acc2[0+nt], a0l, fhhl[nt][s]);  MFMA(acc2[2+nt], a1l, fhhl[nt][s]);
        }
      }
    }
    // combine splits -> f32 gates, exchange via LDS (C/D: col=mn, row=q*4+r)
#pragma unroll
    for (int rt = 0; rt < 2; ++rt)
#pragma unroll
      for (int nt = 0; nt < 2; ++nt) {
        int i = rt*2 + nt;
#pragma unroll
        for (int r = 0; r < 4; ++r) {
          float g = acc0[i][r] + C1*acc1[i][r] + C2*acc2[i][r];
          gate_buf[dhalf*2 + nt][bhalf*32 + rt*16 + q*4 + r][mn] = g;
        }
      }
    __syncthreads();
    // LSTM cell on owned cells (f32, precise libm)
#pragma unroll
    for (int j = 0; j < 4; ++j) {
      int kl = ek0 + j;
      float gi = gate_buf[0][eb][kl] + bias_buf[0][kl];
      float gf = gate_buf[1][eb][kl] + bias_buf[1][kl];
      float gg = gate_buf[2][eb][kl] + bias_buf[2][kl];
      float go = gate_buf[3][eb][kl] + bias_buf[3][kl];
      float c  = sigmf_(gf)*c_reg[j] + sigmf_(gi)*tanhf(gg);
      float h  = sigmf_(go)*tanhf(c);
      c_reg[j] = c;
      int off = eb*HH + p*16 + kl;
      f16 hh = (f16)h;
      hhi[cur^1][off] = hh;
      hlo[cur^1][off] = (f16)((h - (float)hh) * 2048.0f);
    }
    g_arrive(cnt);                 // signals h(t+1) ready  [arrival #(t+1)]
    cur ^= 1;
  }

  // ================= decoder setup (read-only loads; no barrier needed) ====
#pragma unroll
  for (int nt = 0; nt < 2; ++nt) {
    int dl  = dhalf*32 + nt*16 + mn;
    int row = (dl >> 4)*HH + p*16 + (dl & 15);
#pragma unroll
    for (int s = 0; s < 16; ++s)
      split8(dWhh + (size_t)row*HH + s*32 + q*8, fhhh[nt][s], fhhl[nt][s]);
  }
  __syncthreads();   // bias_buf rewrite: ensure no wave still reads enc biases
  if (tid < 64) {
    int g = tid >> 4, kl = tid & 15;
    int r = g*HH + p*16 + kl;
    bias_buf[g][kl] = dBih[r] + dBhh[r];
  }
  __syncthreads();

  // ================= decoder: 64 steps =================
  for (int t = 0; t < TT; ++t) {
    // ---- phase A: cell. x = relu(one_hot(idx)) = one_hot -> column gather ----
    g_wait(cnt, (unsigned)(SS + 2*t) * NWG);    // h(dec t) + idx(t) visible
    f32x4 acc0[4] = {zero4, zero4, zero4, zero4};
    f32x4 acc1[4] = {zero4, zero4, zero4, zero4};
    f32x4 acc2[4] = {zero4, zero4, zero4, zero4};
    {
      const f16* h0h = hhi[cur] + (bhalf*32 + mn)*HH;
      const f16* h0l = hlo[cur] + (bhalf*32 + mn)*HH;
#pragma unroll
      for (int s = 0; s < 16; ++s) {
        f16x8 a0h = ldh8(h0h + s*32 + q*8);
        f16x8 a0l = ldh8(h0l + s*32 + q*8);
        f16x8 a1h = ldh8(h0h + 16*HH + s*32 + q*8);
        f16x8 a1l = ldh8(h0l + 16*HH + s*32 + q*8);
#pragma unroll
        for (int nt = 0; nt < 2; ++nt) {
          MFMA(acc0[0+nt], a0h, fhhh[nt][s]);  MFMA(acc0[2+nt], a1h, fhhh[nt][s]);
          MFMA(acc1[0+nt], a0l, fhhh[nt][s]);  MFMA(acc1[2+nt], a1l, fhhh[nt][s]);
          MFMA(acc1[0+nt], a0h, fhhl[nt][s]);  MFMA(acc1[2+nt], a1h, fhhl[nt][s]);
          MFMA(acc2[0+nt], a0l, fhhl[nt][s]);  MFMA(acc2[2+nt], a1l, fhhl[nt][s]);
        }
      }
    }
#pragma unroll
    for (int rt = 0; rt < 2; ++rt)
#pragma unroll
      for (int nt = 0; nt < 2; ++nt) {
        int i = rt*2 + nt;
#pragma unroll
        for (int r = 0; r < 4; ++r) {
          float g = acc0[i][r] + C1*acc1[i][r] + C2*acc2[i][r];
          gate_buf[dhalf*2 + nt][bhalf*32 + rt*16 + q*4 + r][mn] = g;
        }
      }
    __syncthreads();
    {
      int ib = idxbuf[eb];
#pragma unroll
      for (int j = 0; j < 4; ++j) {
        int kl = ek0 + j;
        int rb = p*16 + kl;
        float gi = gate_buf[0][eb][kl] + bias_buf[0][kl] + dWih[(0*HH + rb)*VV + ib];
        float gf = gate_buf[1][eb][kl] + bias_buf[1][kl] + dWih[(1*HH + rb)*VV + ib];
        float gg = gate_buf[2][eb][kl] + bias_buf[2][kl] + dWih[(2*HH + rb)*VV + ib];
        float go = gate_buf[3][eb][kl] + bias_buf[3][kl] + dWih[(3*HH + rb)*VV + ib];
        float c  = sigmf_(gf)*c_reg[j] + sigmf_(gi)*tanhf(gg);
        float h  = sigmf_(go)*tanhf(c);
        c_reg[j] = c;
        int off = eb*HH + p*16 + kl;
        f16 hh = (f16)h;
        hhi[cur^1][off] = hh;
        hlo[cur^1][off] = (f16)((h - (float)hh) * 2048.0f);
        hf32[cur^1][off] = h;
      }
    }
    g_arrive(cnt);                               // arrival #(SS + 2t + 1)
    int nxt = cur ^ 1;
    g_wait(cnt, (unsigned)(SS + 2*t + 1) * NWG); // hf32(nxt) visible

    // ---- phase B: f64 logits + argmax + log-softmax (waves 0,1; 1 row/wave) ----
    if (w < 2) {
      int b = p*2 + w;
      int v = lane;
      const float* hp = hf32[nxt] + b*HH;
      const float* wr = oW + v*HH;
      double acc = 0.0;
#pragma unroll 4
      for (int kc = 0; kc < 128; ++kc) {
        f32x4 hv = *(const f32x4*)(hp + kc*4);
        f32x4 wv = *(const f32x4*)(wr + kc*4);
        acc += (double)hv[0]*(double)wv[0] + (double)hv[1]*(double)wv[1]
             + (double)hv[2]*(double)wv[2] + (double)hv[3]*(double)wv[3];
      }
      double l = acc + (double)oB[v];
      double mx = l; int ai = v;
#pragma unroll
      for (int o = 32; o > 0; o >>= 1) {
        double om = __shfl_xor(mx, o, 64);
        int    oi = __shfl_xor(ai, o, 64);
        if (om > mx || (om == mx && oi < ai)) { mx = om; ai = oi; }
      }
      double se = exp(l - mx);
#pragma unroll
      for (int o = 32; o > 0; o >>= 1) se += __shfl_xor(se, o, 64);
      double lse = mx + log(se);
      out[((size_t)b*TT + t)*VV + v] = (float)(l - lse);
      if (lane == 0) idxbuf[b] = ai;
    }
    g_arrive(cnt);                               // arrival #(SS + 2t + 2)
    cur = nxt;
  }
}

extern "C" void kernel_launch(void* const* d_in, const int* in_sizes, int n_in,
                              void* d_out, int out_size, void* d_ws, size_t ws_size,
                              hipStream_t stream) {
  (void)in_sizes; (void)n_in; (void)out_size; (void)ws_size;
  // zero: counter + idxbuf + h16 hi/lo double-buffers + hf32 double-buffer
  // (ws is re-poisoned 0xAA before every launch -> must zero every call)
  size_t zbytes = 263168 + 262144;  // = 525312
  hipMemsetAsync(d_ws, 0, zbytes, stream);
  lstm_seq2seq<<<dim3(NWG), dim3(256), 0, stream>>>(
      (const float*)d_in[0],  (const int*)d_in[1],
      (const float*)d_in[2],  (const float*)d_in[3],
      (const float*)d_in[4],  (const float*)d_in[5],
      (const float*)d_in[6],  (const float*)d_in[7],
      (const float*)d_in[8],  (const float*)d_in[9],
      (const float*)d_in[10], (const float*)d_in[11],
      (float*)d_out, (unsigned char*)d_ws);
}